// Round 13
// baseline (61.886 us; speedup 1.0000x reference)
//
#include <hip/hip_runtime.h>
#include <hip/hip_bf16.h>

typedef __attribute__((ext_vector_type(4))) short short4v;
typedef __attribute__((ext_vector_type(4))) float float4v;

#define NHEADS 4
#define DMODEL 64
#define EPSV 1e-5f
#define QSCALE 0.36067376022224085f   // log2(e) / sqrt(16)

__device__ inline short bf16rn(float f) {
    __hip_bfloat16 h = __float2bfloat16(f);
    return __builtin_bit_cast(short, h);
}

__device__ inline float exp2fast(float x) { return __builtin_amdgcn_exp2f(x); }

// ---------- merged projections, 512 threads (validated R9) ----------
__global__ __launch_bounds__(512)
void proj_all_k(const float* __restrict__ Wk, const float* __restrict__ bk,
                const float* __restrict__ Wv, const float* __restrict__ bv,
                const float* __restrict__ Wq, const float* __restrict__ bq,
                const float* __restrict__ fkey, const float* __restrict__ fpix,
                short4v* __restrict__ kfrag, short4v* __restrict__ vfrag,
                short4v* __restrict__ qfrag, int M, int N) {
    __shared__ float xs[64][64];
    __shared__ float wsm[64][65];
    const int t = threadIdx.x;
    const int kvblocks = M >> 6;
    const bool isKV = (int)blockIdx.x < kvblocks;
    const int c0 = (isKV ? blockIdx.x : blockIdx.x - kvblocks) * 64;
    const float* x = isKV ? fkey : fpix;
    const int NC = isKV ? M : N;

    for (int i = t; i < 64 * 64; i += 512) {
        xs[i >> 6][i & 63] = x[(size_t)(i >> 6) * NC + c0 + (i & 63)];
        if (isKV) wsm[i >> 6][i & 63] = Wv[i];
    }
    __syncthreads();
    const int CT = NC >> 4;

    {
        const float* W = isKV ? Wk : Wq;
        const float* b = isKV ? bk : bq;
        const float scale = isKV ? 1.f : QSCALE;
        short4v* outf = isKV ? kfrag : qfrag;
        const int mm = t & 63;
        const int g8 = __builtin_amdgcn_readfirstlane(t >> 6);  // 0..7
        const int qd = g8 >> 1;
        const int half = g8 & 1;
        const int m = c0 + mm;
        float acc[8];
        #pragma unroll
        for (int a = 0; a < 8; ++a)
            acc[a] = b[qd * 16 + (a >> 1) * 4 + half * 2 + (a & 1)];
        #pragma unroll 8
        for (int d = 0; d < 64; ++d) {
            float xv = xs[d][mm];
            #pragma unroll
            for (int a = 0; a < 8; ++a)
                acc[a] = fmaf(W[(qd * 16 + (a >> 1) * 4 + half * 2 + (a & 1)) * 64 + d],
                              xv, acc[a]);
        }
        #pragma unroll
        for (int hh = 0; hh < 2; ++hh) {
            const int h = half * 2 + hh;
            short4v pk;
            #pragma unroll
            for (int j = 0; j < 4; ++j) pk[j] = bf16rn(acc[j * 2 + hh] * scale);
            outf[((size_t)(h * CT + (m >> 4))) * 64 + (m & 15) + 16 * qd] = pk;
        }
    }
    if (isKV) {
        const int lane = t & 63;
        const int w8 = t >> 6;
        const int d = lane >> 2, h = lane & 3;
        const float b0 = bv[lane];
        #pragma unroll
        for (int r = 0; r < 2; ++r) {
            const int mg = r * 8 + w8;
            float a0 = b0, a1 = b0, a2 = b0, a3 = b0;
            #pragma unroll 8
            for (int dd = 0; dd < 64; ++dd) {
                float wv = wsm[lane][dd];
                float4 xv = *(const float4*)&xs[dd][mg * 4];
                a0 = fmaf(wv, xv.x, a0); a1 = fmaf(wv, xv.y, a1);
                a2 = fmaf(wv, xv.z, a2); a3 = fmaf(wv, xv.w, a3);
            }
            short4v pk;
            pk[0] = bf16rn(a0); pk[1] = bf16rn(a1); pk[2] = bf16rn(a2); pk[3] = bf16rn(a3);
            const int m0 = c0 + mg * 4;
            vfrag[((size_t)(h * CT + (m0 >> 4))) * 64 + d + 16 * ((m0 >> 2) & 3)] = pk;
        }
    }
}

// ---------- MFMA flash attention: 8 waves, 2 q-tiles/wave (validated R10) ----------
__global__ __launch_bounds__(512)
void attn_mfma_k(const short4v* __restrict__ qf, const short4v* __restrict__ kf,
                 const short4v* __restrict__ vf, float* __restrict__ xatt,
                 int N, int M) {
    const int lane = threadIdx.x & 63;
    const int ck = threadIdx.x >> 6;
    const int nt0 = blockIdx.x * 2;
    const int h = blockIdx.y;
    const int NT = N >> 4, MT = M >> 4;
    const int mtN = MT >> 3;
    const int mt0 = ck * mtN;

    const short4v qa = qf[((size_t)(h * NT + nt0)) * 64 + lane];
    const short4v qb = qf[((size_t)(h * NT + nt0 + 1)) * 64 + lane];
    const float4v zero4 = {0.f, 0.f, 0.f, 0.f};
    float4v Oa = zero4, Ob = zero4;
    float lda = 0.f, ldb = 0.f;
    const int g4 = (lane >> 4) << 2;

    const short4v* kp = kf + ((size_t)(h * MT + mt0)) * 64 + lane;
    const short4v* vp = vf + ((size_t)(h * MT + mt0)) * 64 + lane;
    for (int it = 0; it < mtN; it += 4) {
        short4v ka[4], va[4];
        #pragma unroll
        for (int u = 0; u < 4; ++u) {
            ka[u] = kp[(it + u) * 64];
            va[u] = vp[(it + u) * 64];
        }
        #pragma unroll
        for (int u = 0; u < 4; ++u) {
            float4v sa = __builtin_amdgcn_mfma_f32_16x16x16bf16_1k(ka[u], qa, zero4, 0, 0, 0);
            float4v sb = __builtin_amdgcn_mfma_f32_16x16x16bf16_1k(ka[u], qb, zero4, 0, 0, 0);
            float pa0 = exp2fast(sa[0]), pa1 = exp2fast(sa[1]),
                  pa2 = exp2fast(sa[2]), pa3 = exp2fast(sa[3]);
            float pb0 = exp2fast(sb[0]), pb1 = exp2fast(sb[1]),
                  pb2 = exp2fast(sb[2]), pb3 = exp2fast(sb[3]);
            lda += (pa0 + pa1) + (pa2 + pa3);
            ldb += (pb0 + pb1) + (pb2 + pb3);
            short4v fa, fb;
            fa[0] = bf16rn(pa0); fa[1] = bf16rn(pa1); fa[2] = bf16rn(pa2); fa[3] = bf16rn(pa3);
            fb[0] = bf16rn(pb0); fb[1] = bf16rn(pb1); fb[2] = bf16rn(pb2); fb[3] = bf16rn(pb3);
            Oa = __builtin_amdgcn_mfma_f32_16x16x16bf16_1k(fa, va[u], Oa, 0, 0, 0);
            Ob = __builtin_amdgcn_mfma_f32_16x16x16bf16_1k(fb, va[u], Ob, 0, 0, 0);
        }
    }
    lda += __shfl_xor(lda, 16); lda += __shfl_xor(lda, 32);
    ldb += __shfl_xor(ldb, 16); ldb += __shfl_xor(ldb, 32);

    __shared__ float Osm[8][512];
    __shared__ float lsm[8][32];
    #pragma unroll
    for (int b = 0; b < 4; ++b) {
        Osm[ck][(g4 + b) * 16 + (lane & 15)]       = Oa[b];
        Osm[ck][256 + (g4 + b) * 16 + (lane & 15)] = Ob[b];
    }
    if (lane < 16) {
        lsm[ck][lane]      = lda;
        lsm[ck][16 + lane] = ldb;
    }
    __syncthreads();

    const int t = threadIdx.x;
    const int j = t >> 8;
    const int tt = t & 255;
    const int d = tt >> 4, q = tt & 15;
    float L = 0.f, val = 0.f;
    #pragma unroll
    for (int c = 0; c < 8; ++c) {
        L   += lsm[c][j * 16 + q];
        val += Osm[c][j * 256 + q * 16 + d];
    }
    xatt[(size_t)(d * NHEADS + h) * N + (nt0 + j) * 16 + q] = val / L;
}

// ---------- latency-tolerant LN finalize from [block][channel] partials ----------
template<int PARTS>
__device__ inline void ln_finalize_fast(const float* __restrict__ pbs,
                                        const float* __restrict__ pbq,
                                        float (*redS)[64], float (*redQ)[64],
                                        float* lnA, float* lnB, int N, int nb) {
    const int tid = threadIdx.x;
    const int c = tid & 63;
    const int part = tid >> 6;      // 0..PARTS-1
    const int per = nb / PARTS;
    const int b0 = part * per;
    float s0 = 0.f, s1 = 0.f, s2 = 0.f, s3 = 0.f;
    float q0 = 0.f, q1 = 0.f, q2 = 0.f, q3 = 0.f;
    int i = 0;
    for (; i + 4 <= per; i += 4) {   // 4 independent streams -> 8 loads in flight
        s0 += pbs[(b0 + i) * 64 + c];     q0 += pbq[(b0 + i) * 64 + c];
        s1 += pbs[(b0 + i + 1) * 64 + c]; q1 += pbq[(b0 + i + 1) * 64 + c];
        s2 += pbs[(b0 + i + 2) * 64 + c]; q2 += pbq[(b0 + i + 2) * 64 + c];
        s3 += pbs[(b0 + i + 3) * 64 + c]; q3 += pbq[(b0 + i + 3) * 64 + c];
    }
    for (; i < per; ++i) {
        s0 += pbs[(b0 + i) * 64 + c];
        q0 += pbq[(b0 + i) * 64 + c];
    }
    redS[part][c] = (s0 + s1) + (s2 + s3);
    redQ[part][c] = (q0 + q1) + (q2 + q3);
    __syncthreads();
    if (tid < 64) {
        float ss = 0.f, qq = 0.f;
        #pragma unroll
        for (int p = 0; p < PARTS; ++p) { ss += redS[p][tid]; qq += redQ[p][tid]; }
        float mean = ss / (float)N;
        float var = qq / (float)N - mean * mean;
        float rstd = rsqrtf(var + EPSV);
        lnA[tid] = rstd;
        lnB[tid] = -mean * rstd;
    }
    __syncthreads();
}

// ---------- conv(Wm) + residual add + LN1 partials (validated R8) ----------
__global__ __launch_bounds__(256)
void conv_wm_resid_k(const float* __restrict__ W, const float* __restrict__ bias,
                     const float* __restrict__ xatt, const float* __restrict__ fpix,
                     float* __restrict__ resid, float* __restrict__ pb_s,
                     float* __restrict__ pb_q, int N) {
    __shared__ float xs[64][64];
    const int tid = threadIdx.x;
    const int bx = blockIdx.x;
    const int n0 = bx * 64;
    for (int i = tid; i < 64 * 64; i += 256) {
        int d = i >> 6, nn = i & 63;
        xs[d][nn] = xatt[(size_t)d * N + n0 + nn];
    }
    __syncthreads();
    const int nn = tid & 63;
    const int og = __builtin_amdgcn_readfirstlane((int)(tid >> 6));
    const int ow = blockIdx.y * 16 + og * 4;
    float acc[4];
    #pragma unroll
    for (int i = 0; i < 4; ++i) acc[i] = bias[ow + i];
    #pragma unroll 8
    for (int d = 0; d < 64; ++d) {
        float xv = xs[d][nn];
        #pragma unroll
        for (int i = 0; i < 4; ++i)
            acc[i] = fmaf(W[(ow + i) * 64 + d], xv, acc[i]);
    }
    #pragma unroll
    for (int i = 0; i < 4; ++i) {
        float r = acc[i] + fpix[(size_t)(ow + i) * N + n0 + nn];
        resid[(size_t)(ow + i) * N + n0 + nn] = r;
        float s = r, q = r * r;
        #pragma unroll
        for (int m = 1; m < 64; m <<= 1) {
            s += __shfl_xor(s, m);
            q += __shfl_xor(q, m);
        }
        if (nn == 0) {
            pb_s[bx * 64 + ow + i] = s;
            pb_q[bx * 64 + ow + i] = q;
        }
    }
}

// ---------- LN1 fast-finalize + normalize + MLP layer 1 (512 thr, grid (N/64,4)) ----------
__global__ __launch_bounds__(512)
void conv1_ln_k(const float* __restrict__ W1, const float* __restrict__ b1,
                const float* __restrict__ resid, const float* __restrict__ pb1s,
                const float* __restrict__ pb1q, float* __restrict__ hbuf, int N) {
    __shared__ float redS[8][64], redQ[8][64];
    __shared__ float lnA[64], lnB[64];
    __shared__ float xs[64][64];
    const int tid = threadIdx.x;
    const int nb = N >> 6;
    ln_finalize_fast<8>(pb1s, pb1q, redS, redQ, lnA, lnB, N, nb);

    const int n0 = blockIdx.x * 64;
    for (int i = tid; i < 64 * 64; i += 512) {
        int c = i >> 6, nn = i & 63;
        xs[c][nn] = resid[(size_t)c * N + n0 + nn] * lnA[c] + lnB[c];
    }
    __syncthreads();

    const int nn = tid & 63;
    const int og = __builtin_amdgcn_readfirstlane((int)(tid >> 6));  // 0..7
    const int h0 = blockIdx.y * 32 + og * 4;
    float acc[4];
    #pragma unroll
    for (int i = 0; i < 4; ++i) acc[i] = b1[h0 + i];
    #pragma unroll 8
    for (int c = 0; c < 64; ++c) {
        float xv = xs[c][nn];
        #pragma unroll
        for (int i = 0; i < 4; ++i)
            acc[i] = fmaf(W1[(h0 + i) * 64 + c], xv, acc[i]);
    }
    #pragma unroll
    for (int i = 0; i < 4; ++i)
        hbuf[(size_t)(h0 + i) * N + n0 + nn] = fmaxf(acc[i], 0.f);
}

// ---------- MLP layer 2 + residual(fea) + LN2 partials (256 thr, grid (N/64,4)) ----------
__global__ __launch_bounds__(256)
void conv2_ln2_k(const float* __restrict__ W2, const float* __restrict__ b2,
                 const float* __restrict__ hbuf, const float* __restrict__ resid,
                 const float* __restrict__ pb1s, const float* __restrict__ pb1q,
                 float* __restrict__ tbuf, float* __restrict__ pb2s,
                 float* __restrict__ pb2q, int N) {
    __shared__ float redS[4][64], redQ[4][64];
    __shared__ float lnA[64], lnB[64];
    __shared__ float hs[128][64];
    const int tid = threadIdx.x;
    const int nb = N >> 6;
    ln_finalize_fast<4>(pb1s, pb1q, redS, redQ, lnA, lnB, N, nb);

    const int bx = blockIdx.x;
    const int n0 = bx * 64;
    for (int i = tid; i < 128 * 64; i += 256) {
        int c = i >> 6, nn = i & 63;
        hs[c][nn] = hbuf[(size_t)c * N + n0 + nn];
    }
    __syncthreads();

    const int nn = tid & 63;
    const int og = __builtin_amdgcn_readfirstlane((int)(tid >> 6));
    const int ow = blockIdx.y * 16 + og * 4;
    float acc[4];
    #pragma unroll
    for (int i = 0; i < 4; ++i) acc[i] = b2[ow + i];
    #pragma unroll 8
    for (int c = 0; c < 128; ++c) {
        float hv = hs[c][nn];
        #pragma unroll
        for (int i = 0; i < 4; ++i)
            acc[i] = fmaf(W2[(ow + i) * 128 + c], hv, acc[i]);
    }
    #pragma unroll
    for (int i = 0; i < 4; ++i) {
        const int o = ow + i;
        float fv = resid[(size_t)o * N + n0 + nn] * lnA[o] + lnB[o];
        float tv = fv + fmaxf(acc[i], 0.f);
        tbuf[(size_t)o * N + n0 + nn] = tv;
        float s = tv, q = tv * tv;
        #pragma unroll
        for (int m = 1; m < 64; m <<= 1) {
            s += __shfl_xor(s, m);
            q += __shfl_xor(q, m);
        }
        if (nn == 0) {
            pb2s[bx * 64 + o] = s;
            pb2q[bx * 64 + o] = q;
        }
    }
}

// ---------- LN2 fast-finalize + normalize -> out (256 thr, grid N/32) ----------
__global__ __launch_bounds__(256)
void ln_finish_k(const float* __restrict__ tbuf, const float* __restrict__ pb2s,
                 const float* __restrict__ pb2q, float* __restrict__ out, int N) {
    __shared__ float redS[4][64], redQ[4][64];
    __shared__ float lnA[64], lnB[64];
    const int tid = threadIdx.x;
    const int nb = N >> 6;
    ln_finalize_fast<4>(pb2s, pb2q, redS, redQ, lnA, lnB, N, nb);
    const int n0 = blockIdx.x * 32;
    for (int i = tid; i < 64 * 32; i += 256) {
        int c = i >> 5, nn = i & 31;
        out[(size_t)c * N + n0 + nn] = tbuf[(size_t)c * N + n0 + nn] * lnA[c] + lnB[c];
    }
}

extern "C" void kernel_launch(void* const* d_in, const int* in_sizes, int n_in,
                              void* d_out, int out_size, void* d_ws, size_t ws_size,
                              hipStream_t stream) {
    const float* fpix = (const float*)d_in[0];
    const float* fkey = (const float*)d_in[1];
    const float* Wq = (const float*)d_in[2];  const float* bq = (const float*)d_in[3];
    const float* Wk = (const float*)d_in[4];  const float* bk = (const float*)d_in[5];
    const float* Wv = (const float*)d_in[6];  const float* bv = (const float*)d_in[7];
    const float* Wm = (const float*)d_in[8];  const float* bm = (const float*)d_in[9];
    const float* W1 = (const float*)d_in[10]; const float* b1 = (const float*)d_in[11];
    const float* W2 = (const float*)d_in[12]; const float* b2 = (const float*)d_in[13];
    float* outp = (float*)d_out;

    const int N = in_sizes[0] / DMODEL;   // 5120
    const int M = in_sizes[1] / DMODEL;   // 4096

    char* wsb = (char*)d_ws;
    short4v* qfrag = (short4v*)(wsb);                   // 655360
    short4v* kfrag = (short4v*)(wsb + 655360);          // 524288
    short4v* vfrag = (short4v*)(wsb + 1179648);         // 524288
    float*   xatt  = (float*)(wsb + 1703936);           // 1310720
    float*   resid = (float*)(wsb + 3014656);           // 1310720
    float*   hbuf  = (float*)(wsb + 4325376);           // 2621440
    float*   tbuf  = (float*)(wsb + 6946816);           // 1310720
    float*   pb1s  = (float*)(wsb + 8257536);           // 20480
    float*   pb1q  = (float*)(wsb + 8278016);           // 20480
    float*   pb2s  = (float*)(wsb + 8298496);           // 20480
    float*   pb2q  = (float*)(wsb + 8318976);           // 20480

    proj_all_k<<<dim3(M / 64 + N / 64), 512, 0, stream>>>(Wk, bk, Wv, bv, Wq, bq,
                                                          fkey, fpix, kfrag, vfrag,
                                                          qfrag, M, N);
    attn_mfma_k<<<dim3(N / 32, NHEADS), 512, 0, stream>>>(qfrag, kfrag, vfrag, xatt, N, M);
    conv_wm_resid_k<<<dim3(N / 64, 4), 256, 0, stream>>>(Wm, bm, xatt, fpix, resid,
                                                         pb1s, pb1q, N);
    conv1_ln_k<<<dim3(N / 64, 4), 512, 0, stream>>>(W1, b1, resid, pb1s, pb1q, hbuf, N);
    conv2_ln2_k<<<dim3(N / 64, 4), 256, 0, stream>>>(W2, b2, hbuf, resid, pb1s, pb1q,
                                                     tbuf, pb2s, pb2q, N);
    ln_finish_k<<<dim3(N / 32), 256, 0, stream>>>(tbuf, pb2s, pb2q, outp, N);
}

// Round 14
// 58.129 us; speedup vs baseline: 1.0646x; 1.0646x over previous
//
#include <hip/hip_runtime.h>
#include <hip/hip_bf16.h>

typedef __attribute__((ext_vector_type(4))) short short4v;
typedef __attribute__((ext_vector_type(4))) float float4v;

#define NHEADS 4
#define DMODEL 64
#define EPSV 1e-5f
#define QSCALE 0.36067376022224085f   // log2(e) / sqrt(16)

__device__ inline short bf16rn(float f) {
    __hip_bfloat16 h = __float2bfloat16(f);
    return __builtin_bit_cast(short, h);
}

__device__ inline float exp2fast(float x) { return __builtin_amdgcn_exp2f(x); }

// ---------- merged projections, 512 threads (validated R9) ----------
__global__ __launch_bounds__(512)
void proj_all_k(const float* __restrict__ Wk, const float* __restrict__ bk,
                const float* __restrict__ Wv, const float* __restrict__ bv,
                const float* __restrict__ Wq, const float* __restrict__ bq,
                const float* __restrict__ fkey, const float* __restrict__ fpix,
                short4v* __restrict__ kfrag, short4v* __restrict__ vfrag,
                short4v* __restrict__ qfrag, int M, int N) {
    __shared__ float xs[64][64];
    __shared__ float wsm[64][65];
    const int t = threadIdx.x;
    const int kvblocks = M >> 6;
    const bool isKV = (int)blockIdx.x < kvblocks;
    const int c0 = (isKV ? blockIdx.x : blockIdx.x - kvblocks) * 64;
    const float* x = isKV ? fkey : fpix;
    const int NC = isKV ? M : N;

    for (int i = t; i < 64 * 64; i += 512) {
        xs[i >> 6][i & 63] = x[(size_t)(i >> 6) * NC + c0 + (i & 63)];
        if (isKV) wsm[i >> 6][i & 63] = Wv[i];
    }
    __syncthreads();
    const int CT = NC >> 4;

    {
        const float* W = isKV ? Wk : Wq;
        const float* b = isKV ? bk : bq;
        const float scale = isKV ? 1.f : QSCALE;
        short4v* outf = isKV ? kfrag : qfrag;
        const int mm = t & 63;
        const int g8 = __builtin_amdgcn_readfirstlane(t >> 6);  // 0..7
        const int qd = g8 >> 1;
        const int half = g8 & 1;
        const int m = c0 + mm;
        float acc[8];
        #pragma unroll
        for (int a = 0; a < 8; ++a)
            acc[a] = b[qd * 16 + (a >> 1) * 4 + half * 2 + (a & 1)];
        #pragma unroll 8
        for (int d = 0; d < 64; ++d) {
            float xv = xs[d][mm];
            #pragma unroll
            for (int a = 0; a < 8; ++a)
                acc[a] = fmaf(W[(qd * 16 + (a >> 1) * 4 + half * 2 + (a & 1)) * 64 + d],
                              xv, acc[a]);
        }
        #pragma unroll
        for (int hh = 0; hh < 2; ++hh) {
            const int h = half * 2 + hh;
            short4v pk;
            #pragma unroll
            for (int j = 0; j < 4; ++j) pk[j] = bf16rn(acc[j * 2 + hh] * scale);
            outf[((size_t)(h * CT + (m >> 4))) * 64 + (m & 15) + 16 * qd] = pk;
        }
    }
    if (isKV) {
        const int lane = t & 63;
        const int w8 = t >> 6;
        const int d = lane >> 2, h = lane & 3;
        const float b0 = bv[lane];
        #pragma unroll
        for (int r = 0; r < 2; ++r) {
            const int mg = r * 8 + w8;
            float a0 = b0, a1 = b0, a2 = b0, a3 = b0;
            #pragma unroll 8
            for (int dd = 0; dd < 64; ++dd) {
                float wv = wsm[lane][dd];
                float4 xv = *(const float4*)&xs[dd][mg * 4];
                a0 = fmaf(wv, xv.x, a0); a1 = fmaf(wv, xv.y, a1);
                a2 = fmaf(wv, xv.z, a2); a3 = fmaf(wv, xv.w, a3);
            }
            short4v pk;
            pk[0] = bf16rn(a0); pk[1] = bf16rn(a1); pk[2] = bf16rn(a2); pk[3] = bf16rn(a3);
            const int m0 = c0 + mg * 4;
            vfrag[((size_t)(h * CT + (m0 >> 4))) * 64 + d + 16 * ((m0 >> 2) & 3)] = pk;
        }
    }
}

// ---------- MFMA flash attention: 8 waves (m-chunks), 2 q-tiles/wave ----------
// grid (N/32, NHEADS), block 512. K/V tile loads shared by both q-tiles.
__global__ __launch_bounds__(512)
void attn_mfma_k(const short4v* __restrict__ qf, const short4v* __restrict__ kf,
                 const short4v* __restrict__ vf, float* __restrict__ xatt,
                 int N, int M) {
    const int lane = threadIdx.x & 63;
    const int ck = threadIdx.x >> 6;          // m-chunk 0..7
    const int nt0 = blockIdx.x * 2;           // q-tiles nt0, nt0+1
    const int h = blockIdx.y;
    const int NT = N >> 4, MT = M >> 4;
    const int mtN = MT >> 3;                  // tiles per chunk (32)
    const int mt0 = ck * mtN;

    const short4v qa = qf[((size_t)(h * NT + nt0)) * 64 + lane];
    const short4v qb = qf[((size_t)(h * NT + nt0 + 1)) * 64 + lane];
    const float4v zero4 = {0.f, 0.f, 0.f, 0.f};
    float4v Oa = zero4, Ob = zero4;
    float lda = 0.f, ldb = 0.f;
    const int g4 = (lane >> 4) << 2;

    const short4v* kp = kf + ((size_t)(h * MT + mt0)) * 64 + lane;
    const short4v* vp = vf + ((size_t)(h * MT + mt0)) * 64 + lane;
    for (int it = 0; it < mtN; it += 4) {
        short4v ka[4], va[4];
        #pragma unroll
        for (int u = 0; u < 4; ++u) {
            ka[u] = kp[(it + u) * 64];
            va[u] = vp[(it + u) * 64];
        }
        #pragma unroll
        for (int u = 0; u < 4; ++u) {
            float4v sa = __builtin_amdgcn_mfma_f32_16x16x16bf16_1k(ka[u], qa, zero4, 0, 0, 0);
            float4v sb = __builtin_amdgcn_mfma_f32_16x16x16bf16_1k(ka[u], qb, zero4, 0, 0, 0);
            float pa0 = exp2fast(sa[0]), pa1 = exp2fast(sa[1]),
                  pa2 = exp2fast(sa[2]), pa3 = exp2fast(sa[3]);
            float pb0 = exp2fast(sb[0]), pb1 = exp2fast(sb[1]),
                  pb2 = exp2fast(sb[2]), pb3 = exp2fast(sb[3]);
            lda += (pa0 + pa1) + (pa2 + pa3);
            ldb += (pb0 + pb1) + (pb2 + pb3);
            short4v fa, fb;
            fa[0] = bf16rn(pa0); fa[1] = bf16rn(pa1); fa[2] = bf16rn(pa2); fa[3] = bf16rn(pa3);
            fb[0] = bf16rn(pb0); fb[1] = bf16rn(pb1); fb[2] = bf16rn(pb2); fb[3] = bf16rn(pb3);
            Oa = __builtin_amdgcn_mfma_f32_16x16x16bf16_1k(fa, va[u], Oa, 0, 0, 0);
            Ob = __builtin_amdgcn_mfma_f32_16x16x16bf16_1k(fb, va[u], Ob, 0, 0, 0);
        }
    }
    // per-query denominator within this chunk (sum the 4 lane groups)
    lda += __shfl_xor(lda, 16); lda += __shfl_xor(lda, 32);
    ldb += __shfl_xor(ldb, 16); ldb += __shfl_xor(ldb, 32);

    __shared__ float Osm[8][512];   // [chunk][j*256 + query*16 + dim]
    __shared__ float lsm[8][32];    // [chunk][j*16 + query]
    #pragma unroll
    for (int b = 0; b < 4; ++b) {
        Osm[ck][(g4 + b) * 16 + (lane & 15)]       = Oa[b];
        Osm[ck][256 + (g4 + b) * 16 + (lane & 15)] = Ob[b];
    }
    if (lane < 16) {
        lsm[ck][lane]      = lda;
        lsm[ck][16 + lane] = ldb;
    }
    __syncthreads();

    const int t = threadIdx.x;
    const int j = t >> 8;                     // which q-tile
    const int tt = t & 255;
    const int d = tt >> 4, q = tt & 15;
    float L = 0.f, val = 0.f;
    #pragma unroll
    for (int c = 0; c < 8; ++c) {
        L   += lsm[c][j * 16 + q];
        val += Osm[c][j * 256 + q * 16 + d];
    }
    xatt[(size_t)(d * NHEADS + h) * N + (nt0 + j) * 16 + q] = val / L;
}

// ---------- conv1x1 (validated R5, unchanged) ----------
template<int DIN, int DOUT, bool RELU>
__global__ __launch_bounds__(256)
void conv1x1_k(const float* __restrict__ W, const float* __restrict__ bias,
               const float* __restrict__ x, float* __restrict__ out, int N) {
    __shared__ float xs[DIN][64];
    const int tid = threadIdx.x;
    const int n0 = blockIdx.x * 64;
    for (int i = tid; i < DIN * 64; i += 256) {
        int d = i >> 6, nn = i & 63;
        xs[d][nn] = x[(size_t)d * N + n0 + nn];
    }
    __syncthreads();
    const int nn = tid & 63;
    const int og = __builtin_amdgcn_readfirstlane((int)(threadIdx.x >> 6));
    const int ow = blockIdx.y * 16 + og * 4;
    float acc[4];
    #pragma unroll
    for (int i = 0; i < 4; ++i) acc[i] = bias[ow + i];
    #pragma unroll 8
    for (int d = 0; d < DIN; ++d) {
        float xv = xs[d][nn];
        #pragma unroll
        for (int i = 0; i < 4; ++i)
            acc[i] = fmaf(W[(ow + i) * DIN + d], xv, acc[i]);
    }
    #pragma unroll
    for (int i = 0; i < 4; ++i) {
        float r = RELU ? fmaxf(acc[i], 0.f) : acc[i];
        out[(size_t)(ow + i) * N + n0 + nn] = r;
    }
}

// ---------- add + LayerNorm over N per channel (validated R5, unchanged) ----------
__global__ __launch_bounds__(512)
void add_ln_k(const float* __restrict__ a, const float* __restrict__ b,
              float* __restrict__ out, int N) {
    const int d = blockIdx.x;
    const int tid = threadIdx.x;
    const int nv = N >> 2;
    const float4* a4 = (const float4*)(a + (size_t)d * N);
    const float4* b4 = (const float4*)(b + (size_t)d * N);
    float4* o4 = (float4*)(out + (size_t)d * N);
    float s1 = 0.f, s2 = 0.f;
    for (int i = tid; i < nv; i += 512) {
        float4 va = a4[i], vb = b4[i];
        float tx = va.x + vb.x, ty = va.y + vb.y, tz = va.z + vb.z, tw = va.w + vb.w;
        s1 += (tx + ty) + (tz + tw);
        s2 = fmaf(tx, tx, s2); s2 = fmaf(ty, ty, s2);
        s2 = fmaf(tz, tz, s2); s2 = fmaf(tw, tw, s2);
    }
    #pragma unroll
    for (int m = 1; m < 64; m <<= 1) {
        s1 += __shfl_xor(s1, m);
        s2 += __shfl_xor(s2, m);
    }
    __shared__ float ws1[8], ws2[8];
    const int w = tid >> 6;
    if ((tid & 63) == 0) { ws1[w] = s1; ws2[w] = s2; }
    __syncthreads();
    s1 = 0.f; s2 = 0.f;
    #pragma unroll
    for (int i = 0; i < 8; ++i) { s1 += ws1[i]; s2 += ws2[i]; }
    const float mean = s1 / (float)N;
    const float var  = s2 / (float)N - mean * mean;
    const float rstd = rsqrtf(var + EPSV);
    for (int i = tid; i < nv; i += 512) {
        float4 va = a4[i], vb = b4[i];
        float4 r;
        r.x = (va.x + vb.x - mean) * rstd;
        r.y = (va.y + vb.y - mean) * rstd;
        r.z = (va.z + vb.z - mean) * rstd;
        r.w = (va.w + vb.w - mean) * rstd;
        o4[i] = r;
    }
}

extern "C" void kernel_launch(void* const* d_in, const int* in_sizes, int n_in,
                              void* d_out, int out_size, void* d_ws, size_t ws_size,
                              hipStream_t stream) {
    const float* fpix = (const float*)d_in[0];
    const float* fkey = (const float*)d_in[1];
    const float* Wq = (const float*)d_in[2];  const float* bq = (const float*)d_in[3];
    const float* Wk = (const float*)d_in[4];  const float* bk = (const float*)d_in[5];
    const float* Wv = (const float*)d_in[6];  const float* bv = (const float*)d_in[7];
    const float* Wm = (const float*)d_in[8];  const float* bm = (const float*)d_in[9];
    const float* W1 = (const float*)d_in[10]; const float* b1 = (const float*)d_in[11];
    const float* W2 = (const float*)d_in[12]; const float* b2 = (const float*)d_in[13];
    float* outp = (float*)d_out;

    const int N = in_sizes[0] / DMODEL;   // 5120
    const int M = in_sizes[1] / DMODEL;   // 4096

    char* wsb = (char*)d_ws;
    short4v* qfrag = (short4v*)(wsb);                   // 655360
    short4v* kfrag = (short4v*)(wsb + 655360);          // 524288
    short4v* vfrag = (short4v*)(wsb + 1179648);         // 524288
    float*   xatt  = (float*)(wsb + 1703936);           // 1310720
    float*   fea   = (float*)(wsb + 3014656);           // 1310720
    float*   attnb = (float*)(wsb + 4325376);           // 1310720
    float*   hbuf  = (float*)(wsb + 5636096);           // 2621440
    float*   mbuf  = (float*)(wsb + 8257536);           // 1310720

    proj_all_k<<<dim3(M / 64 + N / 64), 512, 0, stream>>>(Wk, bk, Wv, bv, Wq, bq,
                                                          fkey, fpix, kfrag, vfrag,
                                                          qfrag, M, N);
    attn_mfma_k<<<dim3(N / 32, NHEADS), 512, 0, stream>>>(qfrag, kfrag, vfrag, xatt, N, M);
    conv1x1_k<64, 64, false><<<dim3(N / 64, 4), 256, 0, stream>>>(Wm, bm, xatt, attnb, N);
    add_ln_k<<<64, 512, 0, stream>>>(fpix, attnb, fea, N);
    conv1x1_k<64, 128, true><<<dim3(N / 64, 8), 256, 0, stream>>>(W1, b1, fea, hbuf, N);
    conv1x1_k<128, 64, true><<<dim3(N / 64, 4), 256, 0, stream>>>(W2, b2, hbuf, mbuf, N);
    add_ln_k<<<64, 512, 0, stream>>>(fea, mbuf, outp, N);
}